// Round 13
// baseline (199.675 us; speedup 1.0000x reference)
//
#include <hip/hip_runtime.h>
#include <cstdint>
#include <cstddef>

#define B_   2
#define L_   4096
#define S_   77
#define TIP_ 16
#define C_   1280
#define CC_  768
#define H_   20

typedef unsigned short u16;
typedef unsigned int   u32;
typedef __attribute__((ext_vector_type(8))) short bf16x8;
typedef __attribute__((ext_vector_type(8))) unsigned short u16x8;
typedef __attribute__((ext_vector_type(4))) float f32x4;

// GEMM shared-memory footprint: Bs[2][160*64] bf16 only (A is reg-direct now)
#define GEMM_SMEM (2*160*64*2)   // 40960 B

// f32 -> bf16 round-to-nearest-even
__device__ __forceinline__ u16 f2bf(float x) {
  u32 u = __float_as_uint(x);
  u32 r = (u + 0x7fffu + ((u >> 16) & 1u)) >> 16;
  return (u16)r;
}

// async global->LDS, 16B per lane (dest = wave-uniform base + lane*16)
__device__ __forceinline__ void gload16(const u16* g, const u16* l) {
  __builtin_amdgcn_global_load_lds(
      (const __attribute__((address_space(1))) u32*)g,
      (__attribute__((address_space(3))) u32*)(uintptr_t)l, 16, 0, 0);
}

// raw barrier: NO implicit vmcnt(0) drain (unlike __syncthreads)
__device__ __forceinline__ void wg_barrier() {
  asm volatile("s_barrier" ::: "memory");
}
template<int N>
__device__ __forceinline__ void vm_wait() {
  asm volatile("s_waitcnt vmcnt(%0)" :: "i"(N) : "memory");
}

// ---------------- prep: flat casts + 5 weight transpose-casts (r12 exact) ----------------
__global__ __launch_bounds__(256) void prep_all(
    const float* __restrict__ X, const float* __restrict__ enc, const float* __restrict__ ip,
    u16* __restrict__ Xbf, u16* __restrict__ encbf, u16* __restrict__ ipbf,
    const float* __restrict__ Wq,  const float* __restrict__ Wk,   const float* __restrict__ Wv,
    const float* __restrict__ Wkip,const float* __restrict__ Wvip,
    u16* __restrict__ WqT, u16* __restrict__ WkT, u16* __restrict__ WvT,
    u16* __restrict__ WkipT, u16* __restrict__ WvipT) {
  __shared__ float tile[32][33];
  const int bid = blockIdx.x;
  if (bid < 2048) {
    const int nX = B_*L_*C_;
    const int nE = B_*S_*CC_;
    const int nI = B_*TIP_*CC_;
    const int total4 = (nX + nE + nI) >> 2;
    for (int i = bid*256 + threadIdx.x; i < total4; i += 2048*256) {
      int idx = i << 2;
      const float* src; u16* dst; int off;
      if (idx < nX)            { src = X;   dst = Xbf;   off = idx; }
      else if (idx < nX + nE)  { src = enc; dst = encbf; off = idx - nX; }
      else                     { src = ip;  dst = ipbf;  off = idx - nX - nE; }
      float4 v = *(const float4*)(src + off);
      ushort4 o;
      o.x = f2bf(v.x); o.y = f2bf(v.y); o.z = f2bf(v.z); o.w = f2bf(v.w);
      *(ushort4*)(dst + off) = o;
    }
    return;
  }
  // transpose-cast: W [K][1280] f32 -> WT [1280][K] bf16
  int t = bid - 2048;
  const float* src; u16* dst; int K;
  if      (t < 1600) { src = Wq;   dst = WqT;   K = C_;  }
  else if (t < 2560) { src = Wk;   dst = WkT;   K = CC_; t -= 1600; }
  else if (t < 3520) { src = Wv;   dst = WvT;   K = CC_; t -= 2560; }
  else if (t < 4480) { src = Wkip; dst = WkipT; K = CC_; t -= 3520; }
  else               { src = Wvip; dst = WvipT; K = CC_; t -= 4480; }
  const int tileK = t / 40, tileN = t % 40;
  const int tx = threadIdx.x & 31, ty = threadIdx.x >> 5;
  const int k0 = tileK*32, n0 = tileN*32;
  #pragma unroll
  for (int r = 0; r < 32; r += 8)
    tile[ty + r][tx] = src[(size_t)(k0 + ty + r)*C_ + n0 + tx];
  __syncthreads();
  #pragma unroll
  for (int r = 0; r < 32; r += 8) {
    const int n = n0 + ty + r, k = k0 + tx;
    dst[(size_t)n*K + k] = f2bf(tile[tx][ty + r]);
  }
}

// ---------------- MFMA bf16 GEMM core: 128x160 tile, BK=64, 8 waves (4x2) ----------------
// r8 sync skeleton EXACTLY (2 raw barriers/kt + counted vmcnt, depth-2 B dbuf).
// NEW: A-fragments are wave-private -> loaded DIRECTLY global->VGPR (like the
// attention kernel's Q frags), prefetched one kt-pair ahead in named reg banks
// avA/avB (unroll-2, static indexing). Cuts LDS-read traffic 28%/kt (the 50%-
// utilized biggest pipe), removes A's DMA+LDS round trip entirely.
// Certification audit (per-wave issue order per body: B-DMA(3), av(4)):
//   steady vm_wait<7>: newer-than-B(kt+1) = B(kt+2)3 + av(kt+2)4 -> B(kt+1)
//   and av(kt+1) certified; barrier makes it collective. Prologue vm_wait<11>
//   certifies B(0) (newer = B(1)3+avA4+avB4). Tail drains vm_wait<0>.
// B keeps slot-XOR swizzle (physical 16B slot = logical ^ (row&7)) via
// pre-swizzled global source + same XOR on ds_read.
template<int MODE, typename OutT>
__device__ __forceinline__ void gemm_core(
    char* smem,
    const u16* __restrict__ A, int lda, int M,
    const u16* __restrict__ BT, int K,
    OutT* __restrict__ Cm,
    const float* __restrict__ bias, const float* __restrict__ resid,
    int mt, int nt) {
  u16* BsB = (u16*)smem;                       // [2][160*64]
  const int tid  = threadIdx.x;                // 0..511
  const int lane = tid & 63, wave = tid >> 6;  // 8 waves
  const int wr = wave >> 1, wc = wave & 1;     // 4x2
  const int lhi = lane >> 4, llo = lane & 15;
  const int lsw = llo & 7;

  f32x4 acc[2][5] = {};

  auto bstage = [&](int kt) {
    u16* Bsb = BsB + (kt & 1)*(160*64);
    #pragma unroll
    for (int it = 0; it < 2; ++it) {
      const int chunk = it*512 + wave*64 + lane;
      const int r = chunk >> 3, c8 = chunk & 7;
      const int g8 = c8 ^ (r & 7);
      const int nrow = nt*160 + r;
      gload16(BT + (size_t)nrow*K + kt*64 + g8*8,
              Bsb + (size_t)(it*512 + wave*64)*8);
    }
    { const int chunk = 1024 + (wave & 3)*64 + lane;   // last 256 pair-duplicated (benign)
      const int r = chunk >> 3, c8 = chunk & 7;
      const int g8 = c8 ^ (r & 7);
      const int nrow = nt*160 + r;
      gload16(BT + (size_t)nrow*K + kt*64 + g8*8,
              Bsb + (size_t)(1024 + (wave & 3)*64)*8);
    }
  };  // 3 DMA loads/thread/stage

  // A fragment row bases (wave-private rows, clamped; garbage rows never stored)
  const u16* arow[2];
  #pragma unroll
  for (int mm = 0; mm < 2; ++mm) {
    int row = mt*128 + wr*32 + mm*16 + llo;
    row = (row < M) ? row : (M - 1);
    arow[mm] = A + (size_t)row*lda;
  }

  auto aload = [&](int kt, bf16x8 av[2][2]) {
    #pragma unroll
    for (int mm = 0; mm < 2; ++mm)
      #pragma unroll
      for (int ks = 0; ks < 2; ++ks)
        av[mm][ks] = *(const bf16x8*)(arow[mm] + kt*64 + ks*32 + lhi*8);
  };  // 4 vector loads/thread

  auto compute = [&](int kt, const bf16x8 av[2][2]) {
    const u16* Bsb = BsB + (kt & 1)*(160*64);
    #pragma unroll
    for (int ks = 0; ks < 2; ++ks) {
      bf16x8 bv[5];
      #pragma unroll
      for (int nn = 0; nn < 5; ++nn) {
        const int row = wc*80 + nn*16 + llo;
        bv[nn] = *(const bf16x8*)(Bsb + row*64 + (((ks*4 + lhi) ^ lsw) << 3));
      }
      __builtin_amdgcn_s_setprio(1);
      #pragma unroll
      for (int mm = 0; mm < 2; ++mm)
        #pragma unroll
        for (int nn = 0; nn < 5; ++nn)
          acc[mm][nn] = __builtin_amdgcn_mfma_f32_16x16x32_bf16(av[mm][ks], bv[nn], acc[mm][nn], 0, 0, 0);
      __builtin_amdgcn_s_setprio(0);
    }
  };

  const int nkt = K >> 6;               // 20 (K=1280) or 12 (K=768), always even
  bf16x8 avA[2][2], avB[2][2];
  bstage(0); bstage(1);
  aload(0, avA); aload(1, avB);
  vm_wait<11>();                        // B(0) certified (B(1)3+avA4+avB4 newer)
  wg_barrier();
  __builtin_amdgcn_sched_barrier(0);

  for (int kt = 0; kt < nkt; kt += 2) {
    // ---- even body: tile kt, regs avA, Bs[0] ----
    compute(kt, avA);
    wg_barrier();                       // all waves done reading Bs[0]
    if (kt + 2 < nkt) {
      bstage(kt + 2);                   // re-stage Bs[0]
      aload(kt + 2, avA);               // WAR on avA ok: already consumed above
      vm_wait<7>();                     // B(kt+1)+av(kt+1) certified
    } else {
      vm_wait<0>();                     // tail drain
    }
    wg_barrier();
    __builtin_amdgcn_sched_barrier(0);
    // ---- odd body: tile kt+1, regs avB, Bs[1] ----
    compute(kt + 1, avB);
    if (kt + 3 < nkt) {
      wg_barrier();                     // all waves done reading Bs[1]
      bstage(kt + 3);
      aload(kt + 3, avB);
      vm_wait<7>();                     // B(kt+2)+av(kt+2) certified
      wg_barrier();
      __builtin_amdgcn_sched_barrier(0);
    }
    // kt+3 >= nkt: final compute, fall through to epilogue
  }

  #pragma unroll
  for (int mm = 0; mm < 2; ++mm) {
    #pragma unroll
    for (int nn = 0; nn < 5; ++nn) {
      const int row0 = mt*128 + wr*32 + mm*16 + lhi*4;
      const int col  = nt*160 + wc*80 + nn*16 + llo;
      #pragma unroll
      for (int r = 0; r < 4; ++r) {
        const int row = row0 + r;
        if (row < M) {
          float v = acc[mm][nn][r];
          if constexpr (MODE == 1) {
            v += bias[col] + resid[(size_t)row*C_ + col];
            Cm[(size_t)row*C_ + col] = v;
          } else {
            Cm[(size_t)row*C_ + col] = f2bf(v);
          }
        }
      }
    }
  }
}

// ---------------- fused Q-GEMM + small projections + Wout transpose (one launch) ----
__global__ __launch_bounds__(512, 4) void gemm_qkv(
    const u16* __restrict__ Xbf, const u16* __restrict__ WqT, u16* __restrict__ Qbf,
    const u16* __restrict__ encbf, const u16* __restrict__ ipbf,
    const u16* __restrict__ WkT, const u16* __restrict__ WvT,
    const u16* __restrict__ WkipT, const u16* __restrict__ WvipT,
    u16* __restrict__ Kbf, u16* __restrict__ Vbf,
    u16* __restrict__ Kipbf, u16* __restrict__ Vipbf,
    const float* __restrict__ Wout, u16* __restrict__ WoutT) {
  __shared__ char smem[GEMM_SMEM];
  const int bid = blockIdx.x;
  if (bid < 512) {
    // bijective XCD swizzle over the 512 Q-blocks (512 % 8 == 0)
    const int swz = (bid & 7) * 64 + (bid >> 3);
    gemm_core<2, u16>(smem, Xbf, C_, B_*L_, WqT, C_, Qbf, nullptr, nullptr, swz >> 3, swz & 7);
    return;
  }
  if (bid < 560) {
    const int t = bid - 512;
    const int zr = t >> 3, nt = t & 7;
    const u16* A; const u16* BT; u16* Cm; int M, mt;
    switch (zr) {
      case 0: A = encbf; BT = WkT;   Cm = Kbf;   M = B_*S_;   mt = 0; break;
      case 1: A = encbf; BT = WkT;   Cm = Kbf;   M = B_*S_;   mt = 1; break;
      case 2: A = encbf; BT = WvT;   Cm = Vbf;   M = B_*S_;   mt = 0; break;
      case 3: A = encbf; BT = WvT;   Cm = Vbf;   M = B_*S_;   mt = 1; break;
      case 4: A = ipbf;  BT = WkipT; Cm = Kipbf; M = B_*TIP_; mt = 0; break;
      default:A = ipbf;  BT = WvipT; Cm = Vipbf; M = B_*TIP_; mt = 0; break;
    }
    gemm_core<2, u16>(smem, A, CC_, M, BT, CC_, Cm, nullptr, nullptr, mt, nt);
    return;
  }
  // Wout transpose-cast: 2 tiles per block, reusing GEMM smem
  const int half = threadIdx.x >> 8;       // 0 or 1
  const int ht   = threadIdx.x & 255;
  const int t2   = (bid - 560)*2 + half;   // tile id 0..1599
  float (*tile)[33] = (float(*)[33])(smem + half*4352);
  const int tileK = t2 / 40, tileN = t2 % 40;
  const int tx = ht & 31, ty = ht >> 5;    // 32 x 8
  const int k0 = tileK*32, n0 = tileN*32;
  #pragma unroll
  for (int r = 0; r < 32; r += 8)
    tile[ty + r][tx] = Wout[(size_t)(k0 + ty + r)*C_ + n0 + tx];
  __syncthreads();
  #pragma unroll
  for (int r = 0; r < 32; r += 8) {
    const int n = n0 + ty + r, k = k0 + tx;
    WoutT[(size_t)n*C_ + k] = f2bf(tile[tx][ty + r]);
  }
}

// out = attn @ Wout + b_out + residual: 512 blocks = exactly 2/CU
__global__ __launch_bounds__(512, 4) void gemm_out(
    const u16* __restrict__ A, const u16* __restrict__ BT,
    float* __restrict__ Cm, const float* __restrict__ bias, const float* __restrict__ resid) {
  __shared__ char smem[GEMM_SMEM];
  const int bid = blockIdx.x;
  const int swz = (bid & 7) * 64 + (bid >> 3);   // 512 % 8 == 0, bijective
  gemm_core<1, float>(smem, A, C_, B_*L_, BT, C_, Cm, bias, resid, swz >> 3, swz & 7);
}

// ---------------- MFMA fused attention (r8 exact: 38.4 KB LDS, 4 blocks/CU) ----
#define KSP   96
#define KLD   72
#define PLD   100
__global__ __launch_bounds__(256) void attn_mfma(
    const u16* __restrict__ Qbf,
    const u16* __restrict__ Kbf,  const u16* __restrict__ Vbf,
    const u16* __restrict__ Kipbf, const u16* __restrict__ Vipbf,
    const float* __restrict__ region, const float* __restrict__ sigma,
    u16* __restrict__ attnbf) {
  __shared__ u16 Vt[64*PLD];        // V transposed [d][s]
  __shared__ u16 R2[128*PLD];       // Kl (96x72) then Pl (128x100)
  u16* Kl = R2;
  u16* Pl = R2;
  const int b = blockIdx.z, h = blockIdx.y;
  const int tid = threadIdx.x, lane = tid & 63, wave = tid >> 6;
  const int llo = lane & 15, lhi = lane >> 4;

  for (int i = tid; i < KSP*8; i += 256) {
    const int r = i >> 3, c8 = i & 7;
    u16x8 val = {0,0,0,0,0,0,0,0};
    if (r < S_)
      val = *(const u16x8*)(Kbf + ((size_t)(b*S_ + r))*C_ + h*64 + c8*8);
    else if (r >= 80)
      val = *(const u16x8*)(Kipbf + ((size_t)(b*TIP_ + r - 80))*C_ + h*64 + c8*8);
    *(u16x8*)(Kl + r*KLD + c8*8) = val;
  }
  for (int c = tid; c < KSP*8; c += 256) {
    const int s = c >> 3, d0 = (c & 7) * 8;
    u16x8 v = {0,0,0,0,0,0,0,0};
    if (s < S_)
      v = *(const u16x8*)(Vbf + ((size_t)(b*S_ + s))*C_ + h*64 + d0);
    else if (s >= 80)
      v = *(const u16x8*)(Vipbf + ((size_t)(b*TIP_ + s - 80))*C_ + h*64 + d0);
    #pragma unroll
    for (int j = 0; j < 8; ++j)
      Vt[(d0 + j)*PLD + s] = v[j];
  }
  __syncthreads();

  const int row0 = blockIdx.x*128 + wave*32;

  bf16x8 av[2][2];
  #pragma unroll
  for (int mm = 0; mm < 2; ++mm)
    #pragma unroll
    for (int ks = 0; ks < 2; ++ks)
      av[mm][ks] = *(const bf16x8*)(Qbf + ((size_t)(b*L_ + row0 + mm*16 + llo))*C_ + h*64 + ks*32 + lhi*8);

  f32x4 acc[2][6] = {};
  #pragma unroll
  for (int ks = 0; ks < 2; ++ks) {
    bf16x8 bv[6];
    #pragma unroll
    for (int nn = 0; nn < 6; ++nn)
      bv[nn] = *(const bf16x8*)(Kl + (nn*16 + llo)*KLD + ks*32 + lhi*8);
    #pragma unroll
    for (int mm = 0; mm < 2; ++mm)
      #pragma unroll
      for (int nn = 0; nn < 6; ++nn)
        acc[mm][nn] = __builtin_amdgcn_mfma_f32_16x16x32_bf16(av[mm][ks], bv[nn], acc[mm][nn], 0, 0, 0);
  }
  __syncthreads();   // all waves' Kl reads done -> R2 becomes Pl

  const float sigscale = sigma[0] * 0.3f;   // REGION_WEIGHT
  const float scale = 0.125f;               // 1/sqrt(64)
  u16* Pw = Pl + wave*32*PLD;

  #pragma unroll
  for (int mm = 0; mm < 2; ++mm) {
    const int rowbase = b*L_ + row0 + mm*16 + lhi*4;
    float sc[5][4];
    float mx[4] = {-1e30f, -1e30f, -1e30f, -1e30f};
    #pragma unroll
    for (int nn = 0; nn < 5; ++nn) {
      const int col = nn*16 + llo;
      #pragma unroll
      for (int r = 0; r < 4; ++r) {
        float v = -1e30f;
        if (col < S_) {
          const float bias = region[((size_t)(rowbase + r))*S_ + col] * sigscale;
          v = fmaf(acc[mm][nn][r], scale, bias);
        }
        sc[nn][r] = v;
        mx[r] = fmaxf(mx[r], v);
      }
    }
    #pragma unroll
    for (int st = 1; st < 16; st <<= 1)
      #pragma unroll
      for (int r = 0; r < 4; ++r)
        mx[r] = fmaxf(mx[r], __shfl_xor(mx[r], st));
    float sum[4] = {0.f, 0.f, 0.f, 0.f};
    #pragma unroll
    for (int nn = 0; nn < 5; ++nn)
      #pragma unroll
      for (int r = 0; r < 4; ++r) {
        const float e = __expf(sc[nn][r] - mx[r]);
        sc[nn][r] = e; sum[r] += e;
      }
    #pragma unroll
    for (int st = 1; st < 16; st <<= 1)
      #pragma unroll
      for (int r = 0; r < 4; ++r)
        sum[r] += __shfl_xor(sum[r], st);
    float inv[4];
    #pragma unroll
    for (int r = 0; r < 4; ++r) inv[r] = 1.f / sum[r];

    float ipe[4], mi[4], sumi[4];
    #pragma unroll
    for (int r = 0; r < 4; ++r) { ipe[r] = acc[mm][5][r] * scale; mi[r] = ipe[r]; }
    #pragma unroll
    for (int st = 1; st < 16; st <<= 1)
      #pragma unroll
      for (int r = 0; r < 4; ++r)
        mi[r] = fmaxf(mi[r], __shfl_xor(mi[r], st));
    #pragma unroll
    for (int r = 0; r < 4; ++r) { ipe[r] = __expf(ipe[r] - mi[r]); sumi[r] = ipe[r]; }
    #pragma unroll
    for (int st = 1; st < 16; st <<= 1)
      #pragma unroll
      for (int r = 0; r < 4; ++r)
        sumi[r] += __shfl_xor(sumi[r], st);

    #pragma unroll
    for (int nn = 0; nn < 5; ++nn)
      #pragma unroll
      for (int r = 0; r < 4; ++r)
        Pw[(mm*16 + lhi*4 + r)*PLD + nn*16 + llo] = f2bf(sc[nn][r] * inv[r]);
    #pragma unroll
    for (int r = 0; r < 4; ++r)
      Pw[(mm*16 + lhi*4 + r)*PLD + 80 + llo] = f2bf(ipe[r] / sumi[r]);
  }

  f32x4 oacc[2][4] = {};
  #pragma unroll
  for (int ks = 0; ks < 3; ++ks) {
    bf16x8 pa[2], vv[4];
    #pragma unroll
    for (int mm = 0; mm < 2; ++mm)
      pa[mm] = *(const bf16x8*)(Pw + (mm*16 + llo)*PLD + ks*32 + lhi*8);
    #pragma unroll
    for (int nn = 0; nn < 4; ++nn)
      vv[nn] = *(const bf16x8*)(Vt + (nn*16 + llo)*PLD + ks*32 + lhi*8);
    #pragma unroll
    for (int mm = 0; mm < 2; ++mm)
      #pragma unroll
      for (int nn = 0; nn < 4; ++nn)
        oacc[mm][nn] = __builtin_amdgcn_mfma_f32_16x16x32_bf16(pa[mm], vv[nn], oacc[mm][nn], 0, 0, 0);
  }

  #pragma unroll
  for (int mm = 0; mm < 2; ++mm)
    #pragma unroll
    for (int nn = 0; nn < 4; ++nn)
      #pragma unroll
      for (int r = 0; r < 4; ++r) {
        const int grow = row0 + mm*16 + lhi*4 + r;
        attnbf[((size_t)(b*L_ + grow))*C_ + h*64 + nn*16 + llo] = f2bf(oacc[mm][nn][r]);
      }
}

// ---------------- launcher ----------------
extern "C" void kernel_launch(void* const* d_in, const int* in_sizes, int n_in,
                              void* d_out, int out_size, void* d_ws, size_t ws_size,
                              hipStream_t stream) {
  const float* hidden = (const float*)d_in[0];
  const float* enc    = (const float*)d_in[1];
  const float* ip     = (const float*)d_in[2];
  const float* region = (const float*)d_in[3];
  const float* sigma  = (const float*)d_in[4];
  const float* Wq     = (const float*)d_in[5];
  const float* Wk     = (const float*)d_in[6];
  const float* Wv     = (const float*)d_in[7];
  const float* Wkip   = (const float*)d_in[8];
  const float* Wvip   = (const float*)d_in[9];
  const float* Wout   = (const float*)d_in[10];
  const float* bout   = (const float*)d_in[11];

  char* base = (char*)d_ws;
  size_t off = 0;
  auto carve = [&](size_t bytes) -> void* {
    void* r = base + off;
    off += (bytes + 255) & ~(size_t)255;
    return r;
  };
  u16* Xbf    = (u16*)carve((size_t)B_*L_*C_*2);
  u16* encbf  = (u16*)carve((size_t)B_*S_*CC_*2);
  u16* ipbf   = (u16*)carve((size_t)B_*TIP_*CC_*2);
  u16* WqT    = (u16*)carve((size_t)C_*C_*2);
  u16* WkT    = (u16*)carve((size_t)C_*CC_*2);
  u16* WvT    = (u16*)carve((size_t)C_*CC_*2);
  u16* WkipT  = (u16*)carve((size_t)C_*CC_*2);
  u16* WvipT  = (u16*)carve((size_t)C_*CC_*2);
  u16* WoutT  = (u16*)carve((size_t)C_*C_*2);
  u16* Qbf    = (u16*)carve((size_t)B_*L_*C_*2);
  u16* Kbf    = (u16*)carve((size_t)B_*S_*C_*2);
  u16* Vbf    = (u16*)carve((size_t)B_*S_*C_*2);
  u16* Kipbf  = (u16*)carve((size_t)B_*TIP_*C_*2);
  u16* Vipbf  = (u16*)carve((size_t)B_*TIP_*C_*2);
  u16* attnbf = (u16*)carve((size_t)B_*L_*C_*2);
  (void)ws_size; (void)in_sizes; (void)n_in; (void)out_size;

  // casts + 5 weight transposes (Wout's lives in gemm_qkv's tail)
  prep_all<<<dim3(2048 + 5440), 256, 0, stream>>>(
      hidden, enc, ip, Xbf, encbf, ipbf,
      Wq, Wk, Wv, Wkip, Wvip,
      WqT, WkT, WvT, WkipT, WvipT);
  // Q = X @ Wq (512) + K/V/K_ip/V_ip projections (48) + Wout transpose (800)
  gemm_qkv<<<dim3(1360), 512, 0, stream>>>(Xbf, WqT, Qbf,
                                           encbf, ipbf, WkT, WvT, WkipT, WvipT,
                                           Kbf, Vbf, Kipbf, Vipbf,
                                           Wout, WoutT);
  // fused MFMA attention (text + IP) -> bf16
  attn_mfma<<<dim3(L_/128, H_, B_), 256, 0, stream>>>(Qbf, Kbf, Vbf, Kipbf, Vipbf,
                                                      region, sigma, attnbf);
  // out = attn @ Wout + b_out + residual
  gemm_out<<<dim3(512), 512, 0, stream>>>(attnbf, WoutT, (float*)d_out, bout, hidden);
}

// Round 14
// 124.787 us; speedup vs baseline: 1.6001x; 1.6001x over previous
//
#include <hip/hip_runtime.h>
#include <cstdint>
#include <cstddef>

#define B_   2
#define L_   4096
#define S_   77
#define TIP_ 16
#define C_   1280
#define CC_  768
#define H_   20

typedef unsigned short u16;
typedef unsigned int   u32;
typedef __attribute__((ext_vector_type(8))) short bf16x8;
typedef __attribute__((ext_vector_type(8))) unsigned short u16x8;
typedef __attribute__((ext_vector_type(4))) float f32x4;

// GEMM shared-memory footprint: As[2][128*64] + Bs[2][160*64], bf16
#define GEMM_SMEM (2*128*64*2 + 2*160*64*2)   // 73728 B -> 2 blocks/CU

// f32 -> bf16 round-to-nearest-even
__device__ __forceinline__ u16 f2bf(float x) {
  u32 u = __float_as_uint(x);
  u32 r = (u + 0x7fffu + ((u >> 16) & 1u)) >> 16;
  return (u16)r;
}

// async global->LDS, 16B per lane (dest = wave-uniform base + lane*16)
__device__ __forceinline__ void gload16(const u16* g, const u16* l) {
  __builtin_amdgcn_global_load_lds(
      (const __attribute__((address_space(1))) u32*)g,
      (__attribute__((address_space(3))) u32*)(uintptr_t)l, 16, 0, 0);
}

// raw barrier: NO implicit vmcnt(0) drain (unlike __syncthreads)
__device__ __forceinline__ void wg_barrier() {
  asm volatile("s_barrier" ::: "memory");
}
template<int N>
__device__ __forceinline__ void vm_wait() {
  asm volatile("s_waitcnt vmcnt(%0)" :: "i"(N) : "memory");
}

// ---------------- prep: flat casts + 5 weight transpose-casts (Wout moved to qkv tail) ----------------
__global__ __launch_bounds__(256) void prep_all(
    const float* __restrict__ X, const float* __restrict__ enc, const float* __restrict__ ip,
    u16* __restrict__ Xbf, u16* __restrict__ encbf, u16* __restrict__ ipbf,
    const float* __restrict__ Wq,  const float* __restrict__ Wk,   const float* __restrict__ Wv,
    const float* __restrict__ Wkip,const float* __restrict__ Wvip,
    u16* __restrict__ WqT, u16* __restrict__ WkT, u16* __restrict__ WvT,
    u16* __restrict__ WkipT, u16* __restrict__ WvipT) {
  __shared__ float tile[32][33];
  const int bid = blockIdx.x;
  if (bid < 2048) {
    const int nX = B_*L_*C_;
    const int nE = B_*S_*CC_;
    const int nI = B_*TIP_*CC_;
    const int total4 = (nX + nE + nI) >> 2;
    for (int i = bid*256 + threadIdx.x; i < total4; i += 2048*256) {
      int idx = i << 2;
      const float* src; u16* dst; int off;
      if (idx < nX)            { src = X;   dst = Xbf;   off = idx; }
      else if (idx < nX + nE)  { src = enc; dst = encbf; off = idx - nX; }
      else                     { src = ip;  dst = ipbf;  off = idx - nX - nE; }
      float4 v = *(const float4*)(src + off);
      ushort4 o;
      o.x = f2bf(v.x); o.y = f2bf(v.y); o.z = f2bf(v.z); o.w = f2bf(v.w);
      *(ushort4*)(dst + off) = o;
    }
    return;
  }
  // transpose-cast: W [K][1280] f32 -> WT [1280][K] bf16
  int t = bid - 2048;
  const float* src; u16* dst; int K;
  if      (t < 1600) { src = Wq;   dst = WqT;   K = C_;  }
  else if (t < 2560) { src = Wk;   dst = WkT;   K = CC_; t -= 1600; }
  else if (t < 3520) { src = Wv;   dst = WvT;   K = CC_; t -= 2560; }
  else if (t < 4480) { src = Wkip; dst = WkipT; K = CC_; t -= 3520; }
  else               { src = Wvip; dst = WvipT; K = CC_; t -= 4480; }
  const int tileK = t / 40, tileN = t % 40;
  const int tx = threadIdx.x & 31, ty = threadIdx.x >> 5;
  const int k0 = tileK*32, n0 = tileN*32;
  #pragma unroll
  for (int r = 0; r < 32; r += 8)
    tile[ty + r][tx] = src[(size_t)(k0 + ty + r)*C_ + n0 + tx];
  __syncthreads();
  #pragma unroll
  for (int r = 0; r < 32; r += 8) {
    const int n = n0 + ty + r, k = k0 + tx;
    dst[(size_t)n*K + k] = f2bf(tile[tx][ty + r]);
  }
}

// ---------------- MFMA bf16 GEMM core: 128x160 tile, BK=64, 8 waves (4x2) ----------------
// r8/r11/r12 skeleton EXACTLY (proven 43.7us; 6 restructures all regressed):
// compiler-scheduled compute, depth-2 counted-vmcnt, 2 raw barriers/kt,
// slot-XOR swizzle (physical 16B slot = logical ^ (row&7), via pre-swizzled
// global source + same XOR on ds_read). smem caller-provided so tail paths
// can reuse the block's LDS without raising static footprint.
template<int MODE, typename OutT>
__device__ __forceinline__ void gemm_core(
    char* smem,
    const u16* __restrict__ A, int lda, int M,
    const u16* __restrict__ BT, int K,
    OutT* __restrict__ Cm,
    const float* __restrict__ bias, const float* __restrict__ resid,
    int mt, int nt) {
  u16* AsB = (u16*)smem;                       // [2][128*64]
  u16* BsB = (u16*)(smem + 2*128*64*2);        // [2][160*64]
  const int tid  = threadIdx.x;                // 0..511
  const int lane = tid & 63, wave = tid >> 6;  // 8 waves
  const int wr = wave >> 1, wc = wave & 1;     // 4x2
  const int lhi = lane >> 4, llo = lane & 15;
  const int lsw = llo & 7;

  f32x4 acc[2][5] = {};

  auto stage = [&](int kt) {
    u16* Asb = AsB + (kt & 1)*(128*64);
    u16* Bsb = BsB + (kt & 1)*(160*64);
    #pragma unroll
    for (int it = 0; it < 2; ++it) {
      const int chunk = it*512 + wave*64 + lane;
      const int r = chunk >> 3, c8 = chunk & 7;
      const int g8 = c8 ^ (r & 7);
      int row_g = mt*128 + r; row_g = (row_g < M) ? row_g : (M - 1);
      gload16(A + (size_t)row_g*lda + kt*64 + g8*8,
              Asb + (size_t)(it*512 + wave*64)*8);
    }
    #pragma unroll
    for (int it = 0; it < 2; ++it) {
      const int chunk = it*512 + wave*64 + lane;
      const int r = chunk >> 3, c8 = chunk & 7;
      const int g8 = c8 ^ (r & 7);
      const int nrow = nt*160 + r;
      gload16(BT + (size_t)nrow*K + kt*64 + g8*8,
              Bsb + (size_t)(it*512 + wave*64)*8);
    }
    { const int chunk = 1024 + (wave & 3)*64 + lane;   // last 256 pair-duplicated (benign)
      const int r = chunk >> 3, c8 = chunk & 7;
      const int g8 = c8 ^ (r & 7);
      const int nrow = nt*160 + r;
      gload16(BT + (size_t)nrow*K + kt*64 + g8*8,
              Bsb + (size_t)(1024 + (wave & 3)*64)*8);
    }
  };  // LP = 5 loads/thread/stage

  auto compute = [&](int kt) {
    const u16* Asb = AsB + (kt & 1)*(128*64);
    const u16* Bsb = BsB + (kt & 1)*(160*64);
    #pragma unroll
    for (int ks = 0; ks < 2; ++ks) {
      bf16x8 av[2], bv[5];
      #pragma unroll
      for (int mm = 0; mm < 2; ++mm) {
        const int row = wr*32 + mm*16 + llo;
        av[mm] = *(const bf16x8*)(Asb + row*64 + (((ks*4 + lhi) ^ lsw) << 3));
      }
      #pragma unroll
      for (int nn = 0; nn < 5; ++nn) {
        const int row = wc*80 + nn*16 + llo;
        bv[nn] = *(const bf16x8*)(Bsb + row*64 + (((ks*4 + lhi) ^ lsw) << 3));
      }
      __builtin_amdgcn_s_setprio(1);
      #pragma unroll
      for (int mm = 0; mm < 2; ++mm)
        #pragma unroll
        for (int nn = 0; nn < 5; ++nn)
          acc[mm][nn] = __builtin_amdgcn_mfma_f32_16x16x32_bf16(av[mm], bv[nn], acc[mm][nn], 0, 0, 0);
      __builtin_amdgcn_s_setprio(0);
    }
  };

  const int nkt = K >> 6;               // 20 (K=1280) or 12 (K=768)
  stage(0);
  stage(1);
  vm_wait<5>();                         // own batch-0 loads done
  wg_barrier();                         // collective: buf0 ready
  __builtin_amdgcn_sched_barrier(0);

  for (int kt = 0; kt < nkt; ++kt) {
    compute(kt);
    if (kt + 2 < nkt) {
      wg_barrier();                     // all waves done reading buf kt&1
      stage(kt + 2);                    // overwrite it
      vm_wait<5>();                     // own batch kt+1 done
      wg_barrier();                     // collective: buf (kt+1)&1 ready
      __builtin_amdgcn_sched_barrier(0);
    } else if (kt + 1 < nkt) {
      vm_wait<0>();                     // tail drain (no re-stage)
      wg_barrier();
      __builtin_amdgcn_sched_barrier(0);
    }
  }

  #pragma unroll
  for (int mm = 0; mm < 2; ++mm) {
    #pragma unroll
    for (int nn = 0; nn < 5; ++nn) {
      const int row0 = mt*128 + wr*32 + mm*16 + lhi*4;
      const int col  = nt*160 + wc*80 + nn*16 + llo;
      #pragma unroll
      for (int r = 0; r < 4; ++r) {
        const int row = row0 + r;
        if (row < M) {
          float v = acc[mm][nn][r];
          if constexpr (MODE == 1) {
            v += bias[col] + resid[(size_t)row*C_ + col];
            Cm[(size_t)row*C_ + col] = v;
          } else {
            Cm[(size_t)row*C_ + col] = f2bf(v);
          }
        }
      }
    }
  }
}

// ---------------- fused Q-GEMM + small projections + Wout transpose (one launch) ----
// bid <  512: Q = X @ Wq tile (64 m x 8 n, XCD-swizzled, 2/CU).
// bid <  560: one of 48 projection tiles (K/V/K_ip/V_ip) — Q retirement tail.
// bid >= 560: 800 blocks x 2 Wout 32x32 transpose tiles (feeds gemm_out, two
//             launches later; zero deps on prep) — also hidden in the tail.
__global__ __launch_bounds__(512, 4) void gemm_qkv(
    const u16* __restrict__ Xbf, const u16* __restrict__ WqT, u16* __restrict__ Qbf,
    const u16* __restrict__ encbf, const u16* __restrict__ ipbf,
    const u16* __restrict__ WkT, const u16* __restrict__ WvT,
    const u16* __restrict__ WkipT, const u16* __restrict__ WvipT,
    u16* __restrict__ Kbf, u16* __restrict__ Vbf,
    u16* __restrict__ Kipbf, u16* __restrict__ Vipbf,
    const float* __restrict__ Wout, u16* __restrict__ WoutT) {
  __shared__ char smem[GEMM_SMEM];
  const int bid = blockIdx.x;
  if (bid < 512) {
    // bijective XCD swizzle over the 512 Q-blocks (512 % 8 == 0)
    const int swz = (bid & 7) * 64 + (bid >> 3);
    gemm_core<2, u16>(smem, Xbf, C_, B_*L_, WqT, C_, Qbf, nullptr, nullptr, swz >> 3, swz & 7);
    return;
  }
  if (bid < 560) {
    const int t = bid - 512;
    const int zr = t >> 3, nt = t & 7;
    const u16* A; const u16* BT; u16* Cm; int M, mt;
    switch (zr) {
      case 0: A = encbf; BT = WkT;   Cm = Kbf;   M = B_*S_;   mt = 0; break;
      case 1: A = encbf; BT = WkT;   Cm = Kbf;   M = B_*S_;   mt = 1; break;
      case 2: A = encbf; BT = WvT;   Cm = Vbf;   M = B_*S_;   mt = 0; break;
      case 3: A = encbf; BT = WvT;   Cm = Vbf;   M = B_*S_;   mt = 1; break;
      case 4: A = ipbf;  BT = WkipT; Cm = Kipbf; M = B_*TIP_; mt = 0; break;
      default:A = ipbf;  BT = WvipT; Cm = Vipbf; M = B_*TIP_; mt = 0; break;
    }
    gemm_core<2, u16>(smem, A, CC_, M, BT, CC_, Cm, nullptr, nullptr, mt, nt);
    return;
  }
  // Wout transpose-cast: 2 tiles per block (threads 0-255 / 256-511),
  // reusing the GEMM smem block (no extra static LDS).
  const int half = threadIdx.x >> 8;       // 0 or 1
  const int ht   = threadIdx.x & 255;
  const int t2   = (bid - 560)*2 + half;   // tile id 0..1599
  float (*tile)[33] = (float(*)[33])(smem + half*4352);
  const int tileK = t2 / 40, tileN = t2 % 40;
  const int tx = ht & 31, ty = ht >> 5;    // 32 x 8
  const int k0 = tileK*32, n0 = tileN*32;
  #pragma unroll
  for (int r = 0; r < 32; r += 8)
    tile[ty + r][tx] = Wout[(size_t)(k0 + ty + r)*C_ + n0 + tx];
  __syncthreads();
  #pragma unroll
  for (int r = 0; r < 32; r += 8) {
    const int n = n0 + ty + r, k = k0 + tx;
    WoutT[(size_t)n*C_ + k] = f2bf(tile[tx][ty + r]);
  }
}

// out = attn @ Wout + b_out + residual: 512 blocks = exactly 2/CU
__global__ __launch_bounds__(512, 4) void gemm_out(
    const u16* __restrict__ A, const u16* __restrict__ BT,
    float* __restrict__ Cm, const float* __restrict__ bias, const float* __restrict__ resid) {
  __shared__ char smem[GEMM_SMEM];
  const int bid = blockIdx.x;
  const int swz = (bid & 7) * 64 + (bid >> 3);   // 512 % 8 == 0, bijective
  gemm_core<1, float>(smem, A, C_, B_*L_, BT, C_, Cm, bias, resid, swz >> 3, swz & 7);
}

// ---------------- MFMA fused attention (r8 exact: 38.4 KB LDS, 4 blocks/CU) ----
// Unified key space of 96: [0,77)=text keys, [77,80)=zero pad, [80,96)=IP keys.
// LDS: Vt[64][100] + R2 = Kl (stride 72) then Pl (stride 100); K dead after
// QK^T, one __syncthreads certifies reads; P slices wave-private.
#define KSP   96
#define KLD   72
#define PLD   100
__global__ __launch_bounds__(256) void attn_mfma(
    const u16* __restrict__ Qbf,
    const u16* __restrict__ Kbf,  const u16* __restrict__ Vbf,
    const u16* __restrict__ Kipbf, const u16* __restrict__ Vipbf,
    const float* __restrict__ region, const float* __restrict__ sigma,
    u16* __restrict__ attnbf) {
  __shared__ u16 Vt[64*PLD];        // V transposed [d][s]
  __shared__ u16 R2[128*PLD];       // Kl (96x72) then Pl (128x100)
  u16* Kl = R2;
  u16* Pl = R2;
  const int b = blockIdx.z, h = blockIdx.y;
  const int tid = threadIdx.x, lane = tid & 63, wave = tid >> 6;
  const int llo = lane & 15, lhi = lane >> 4;

  for (int i = tid; i < KSP*8; i += 256) {
    const int r = i >> 3, c8 = i & 7;
    u16x8 val = {0,0,0,0,0,0,0,0};
    if (r < S_)
      val = *(const u16x8*)(Kbf + ((size_t)(b*S_ + r))*C_ + h*64 + c8*8);
    else if (r >= 80)
      val = *(const u16x8*)(Kipbf + ((size_t)(b*TIP_ + r - 80))*C_ + h*64 + c8*8);
    *(u16x8*)(Kl + r*KLD + c8*8) = val;
  }
  for (int c = tid; c < KSP*8; c += 256) {
    const int s = c >> 3, d0 = (c & 7) * 8;
    u16x8 v = {0,0,0,0,0,0,0,0};
    if (s < S_)
      v = *(const u16x8*)(Vbf + ((size_t)(b*S_ + s))*C_ + h*64 + d0);
    else if (s >= 80)
      v = *(const u16x8*)(Vipbf + ((size_t)(b*TIP_ + s - 80))*C_ + h*64 + d0);
    #pragma unroll
    for (int j = 0; j < 8; ++j)
      Vt[(d0 + j)*PLD + s] = v[j];
  }
  __syncthreads();

  const int row0 = blockIdx.x*128 + wave*32;

  bf16x8 av[2][2];
  #pragma unroll
  for (int mm = 0; mm < 2; ++mm)
    #pragma unroll
    for (int ks = 0; ks < 2; ++ks)
      av[mm][ks] = *(const bf16x8*)(Qbf + ((size_t)(b*L_ + row0 + mm*16 + llo))*C_ + h*64 + ks*32 + lhi*8);

  f32x4 acc[2][6] = {};
  #pragma unroll
  for (int ks = 0; ks < 2; ++ks) {
    bf16x8 bv[6];
    #pragma unroll
    for (int nn = 0; nn < 6; ++nn)
      bv[nn] = *(const bf16x8*)(Kl + (nn*16 + llo)*KLD + ks*32 + lhi*8);
    #pragma unroll
    for (int mm = 0; mm < 2; ++mm)
      #pragma unroll
      for (int nn = 0; nn < 6; ++nn)
        acc[mm][nn] = __builtin_amdgcn_mfma_f32_16x16x32_bf16(av[mm][ks], bv[nn], acc[mm][nn], 0, 0, 0);
  }
  __syncthreads();   // all waves' Kl reads done -> R2 becomes Pl

  const float sigscale = sigma[0] * 0.3f;   // REGION_WEIGHT
  const float scale = 0.125f;               // 1/sqrt(64)
  u16* Pw = Pl + wave*32*PLD;

  #pragma unroll
  for (int mm = 0; mm < 2; ++mm) {
    const int rowbase = b*L_ + row0 + mm*16 + lhi*4;
    float sc[5][4];
    float mx[4] = {-1e30f, -1e30f, -1e30f, -1e30f};
    #pragma unroll
    for (int nn = 0; nn < 5; ++nn) {
      const int col = nn*16 + llo;
      #pragma unroll
      for (int r = 0; r < 4; ++r) {
        float v = -1e30f;
        if (col < S_) {
          const float bias = region[((size_t)(rowbase + r))*S_ + col] * sigscale;
          v = fmaf(acc[mm][nn][r], scale, bias);
        }
        sc[nn][r] = v;
        mx[r] = fmaxf(mx[r], v);
      }
    }
    #pragma unroll
    for (int st = 1; st < 16; st <<= 1)
      #pragma unroll
      for (int r = 0; r < 4; ++r)
        mx[r] = fmaxf(mx[r], __shfl_xor(mx[r], st));
    float sum[4] = {0.f, 0.f, 0.f, 0.f};
    #pragma unroll
    for (int nn = 0; nn < 5; ++nn)
      #pragma unroll
      for (int r = 0; r < 4; ++r) {
        const float e = __expf(sc[nn][r] - mx[r]);
        sc[nn][r] = e; sum[r] += e;
      }
    #pragma unroll
    for (int st = 1; st < 16; st <<= 1)
      #pragma unroll
      for (int r = 0; r < 4; ++r)
        sum[r] += __shfl_xor(sum[r], st);
    float inv[4];
    #pragma unroll
    for (int r = 0; r < 4; ++r) inv[r] = 1.f / sum[r];

    float ipe[4], mi[4], sumi[4];
    #pragma unroll
    for (int r = 0; r < 4; ++r) { ipe[r] = acc[mm][5][r] * scale; mi[r] = ipe[r]; }
    #pragma unroll
    for (int st = 1; st < 16; st <<= 1)
      #pragma unroll
      for (int r = 0; r < 4; ++r)
        mi[r] = fmaxf(mi[r], __shfl_xor(mi[r], st));
    #pragma unroll
    for (int r = 0; r < 4; ++r) { ipe[r] = __expf(ipe[r] - mi[r]); sumi[r] = ipe[r]; }
    #pragma unroll
    for (int st = 1; st < 16; st <<= 1)
      #pragma unroll
      for (int r = 0; r < 4; ++r)
        sumi[r] += __shfl_xor(sumi[r], st);

    #pragma unroll
    for (int nn = 0; nn < 5; ++nn)
      #pragma unroll
      for (int r = 0; r < 4; ++r)
        Pw[(mm*16 + lhi*4 + r)*PLD + nn*16 + llo] = f2bf(sc[nn][r] * inv[r]);
    #pragma unroll
    for (int r = 0; r < 4; ++r)
      Pw[(mm*16 + lhi*4 + r)*PLD + 80 + llo] = f2bf(ipe[r] / sumi[r]);
  }

  f32x4 oacc[2][4] = {};
  #pragma unroll
  for (int ks = 0; ks < 3; ++ks) {
    bf16x8 pa[2], vv[4];
    #pragma unroll
    for (int mm = 0; mm < 2; ++mm)
      pa[mm] = *(const bf16x8*)(Pw + (mm*16 + llo)*PLD + ks*32 + lhi*8);
    #pragma unroll
    for (int nn = 0; nn < 4; ++nn)
      vv[nn] = *(const bf16x8*)(Vt + (nn*16 + llo)*PLD + ks*32 + lhi*8);
    #pragma unroll
    for (int mm = 0; mm < 2; ++mm)
      #pragma unroll
      for (int nn = 0; nn < 4; ++nn)
        oacc[mm][nn] = __builtin_amdgcn_mfma_f32_16x16x32_bf16(pa[mm], vv[nn], oacc[mm][nn], 0, 0, 0);
  }

  #pragma unroll
  for (int mm = 0; mm < 2; ++mm)
    #pragma unroll
    for (int nn = 0; nn < 4; ++nn)
      #pragma unroll
      for (int r = 0; r < 4; ++r) {
        const int grow = row0 + mm*16 + lhi*4 + r;
        attnbf[((size_t)(b*L_ + grow))*C_ + h*64 + nn*16 + llo] = f2bf(oacc[mm][nn][r]);
      }
}

// ---------------- launcher ----------------
extern "C" void kernel_launch(void* const* d_in, const int* in_sizes, int n_in,
                              void* d_out, int out_size, void* d_ws, size_t ws_size,
                              hipStream_t stream) {
  const float* hidden = (const float*)d_in[0];
  const float* enc    = (const float*)d_in[1];
  const float* ip     = (const float*)d_in[2];
  const float* region = (const float*)d_in[3];
  const float* sigma  = (const float*)d_in[4];
  const float* Wq     = (const float*)d_in[5];
  const float* Wk     = (const float*)d_in[6];
  const float* Wv     = (const float*)d_in[7];
  const float* Wkip   = (const float*)d_in[8];
  const float* Wvip   = (const float*)d_in[9];
  const float* Wout   = (const float*)d_in[10];
  const float* bout   = (const float*)d_in[11];

  char* base = (char*)d_ws;
  size_t off = 0;
  auto carve = [&](size_t bytes) -> void* {
    void* r = base + off;
    off += (bytes + 255) & ~(size_t)255;
    return r;
  };
  u16* Xbf    = (u16*)carve((size_t)B_*L_*C_*2);
  u16* encbf  = (u16*)carve((size_t)B_*S_*CC_*2);
  u16* ipbf   = (u16*)carve((size_t)B_*TIP_*CC_*2);
  u16* WqT    = (u16*)carve((size_t)C_*C_*2);
  u16* WkT    = (u16*)carve((size_t)C_*CC_*2);
  u16* WvT    = (u16*)carve((size_t)C_*CC_*2);
  u16* WkipT  = (u16*)carve((size_t)C_*CC_*2);
  u16* WvipT  = (u16*)carve((size_t)C_*CC_*2);
  u16* WoutT  = (u16*)carve((size_t)C_*C_*2);
  u16* Qbf    = (u16*)carve((size_t)B_*L_*C_*2);
  u16* Kbf    = (u16*)carve((size_t)B_*S_*C_*2);
  u16* Vbf    = (u16*)carve((size_t)B_*S_*C_*2);
  u16* Kipbf  = (u16*)carve((size_t)B_*TIP_*C_*2);
  u16* Vipbf  = (u16*)carve((size_t)B_*TIP_*C_*2);
  u16* attnbf = (u16*)carve((size_t)B_*L_*C_*2);
  (void)ws_size; (void)in_sizes; (void)n_in; (void)out_size;

  // casts + 5 weight transposes (Wout's lives in gemm_qkv's tail)
  prep_all<<<dim3(2048 + 5440), 256, 0, stream>>>(
      hidden, enc, ip, Xbf, encbf, ipbf,
      Wq, Wk, Wv, Wkip, Wvip,
      WqT, WkT, WvT, WkipT, WvipT);
  // Q = X @ Wq (512) + K/V/K_ip/V_ip projections (48) + Wout transpose (800)
  gemm_qkv<<<dim3(1360), 512, 0, stream>>>(Xbf, WqT, Qbf,
                                           encbf, ipbf, WkT, WvT, WkipT, WvipT,
                                           Kbf, Vbf, Kipbf, Vipbf,
                                           Wout, WoutT);
  // fused MFMA attention (text + IP) -> bf16
  attn_mfma<<<dim3(L_/128, H_, B_), 256, 0, stream>>>(Qbf, Kbf, Vbf, Kipbf, Vipbf,
                                                      region, sigma, attnbf);
  // out = attn @ Wout + b_out + residual
  gemm_out<<<dim3(512), 512, 0, stream>>>(attnbf, WoutT, (float*)d_out, bout, hidden);
}